// Round 7
// baseline (247.659 us; speedup 1.0000x reference)
//
#include <hip/hip_runtime.h>

#define AS1 __attribute__((address_space(1)))
#define AS3 __attribute__((address_space(3)))

typedef __attribute__((ext_vector_type(8))) short short8;
typedef __attribute__((ext_vector_type(4))) float floatx4;

// ---- bf16 helpers (RNE; inputs are finite, no NaN/Inf handling needed) ----
__device__ __forceinline__ short f2bf(float f) {
  union { float f; unsigned u; } v; v.f = f;
  return (short)((v.u + 0x7fffu + ((v.u >> 16) & 1u)) >> 16);
}
__device__ __forceinline__ float bf2f(short s) {
  union { unsigned u; float f; } v; v.u = ((unsigned)(unsigned short)s) << 16;
  return v.f;
}

// ---- async global->LDS, 16B per lane (wave-uniform LDS base + lane*16) ----
__device__ __forceinline__ void gload_lds16(const void* g, void* l) {
  __builtin_amdgcn_global_load_lds((const AS1 unsigned*)g, (AS3 unsigned*)l, 16, 0, 0);
}

// Stage a 128x64 bf16 tile (rows rowBase..+127, cols kBase..+63) of row-major G
// (leading dim `ld` elements) into contiguous 128x64 LDS. 256 threads / 4 waves.
__device__ __forceinline__ void stage128x64(const short* __restrict__ G, long rowBase, long ld,
                                            int kBase, short* lds, int lane, int wave) {
  const short* gb = G + rowBase * ld + (long)kBase + (long)(lane >> 3) * ld + (lane & 7) * 8;
#pragma unroll
  for (int j = 0; j < 4; ++j) {
    int c = wave * 4 + j;
    gload_lds16(gb + (long)c * 8 * ld, lds + c * 512);
  }
}

// One BK=64 step of 128x128 MFMA tile compute. Wave (wm,wn) owns a 64x64 C block.
__device__ __forceinline__ void mfma_step(const short* lA, const short* lB, floatx4 acc[4][4],
                                          int lane, int wm, int wn) {
#pragma unroll
  for (int kk = 0; kk < 64; kk += 32) {
    short8 a[4], b[4];
    int kq = kk + (lane >> 4) * 8;
#pragma unroll
    for (int i = 0; i < 4; ++i) {
      a[i] = *(const short8*)(lA + (wm * 64 + i * 16 + (lane & 15)) * 64 + kq);
      b[i] = *(const short8*)(lB + (wn * 64 + i * 16 + (lane & 15)) * 64 + kq);
    }
#pragma unroll
    for (int i = 0; i < 4; ++i)
#pragma unroll
      for (int j = 0; j < 4; ++j)
        acc[i][j] = __builtin_amdgcn_mfma_f32_16x16x32_bf16(a[i], b[j], acc[i][j], 0, 0, 0);
  }
}

// Causal (qt,kt) pair LUT, supertile-major order. Entry = (qt<<4)|kt.
// Class r (=blockIdx.x%8, i.e. XCD r under round-robin dispatch) processes
// entries [r*17, r*17+17): exactly 17 pairs per XCD (perfect balance), and each
// class spans <=3 supertiles (Q/K strip locality mostly preserved).
__device__ const unsigned char PAIR_LUT[136] = {
  // s(1,0) 16
  0x40,0x41,0x42,0x43,0x50,0x51,0x52,0x53,0x60,0x61,0x62,0x63,0x70,0x71,0x72,0x73,
  // s(2,0) 16
  0x80,0x81,0x82,0x83,0x90,0x91,0x92,0x93,0xA0,0xA1,0xA2,0xA3,0xB0,0xB1,0xB2,0xB3,
  // s(2,1) 16
  0x84,0x85,0x86,0x87,0x94,0x95,0x96,0x97,0xA4,0xA5,0xA6,0xA7,0xB4,0xB5,0xB6,0xB7,
  // s(3,0) 16
  0xC0,0xC1,0xC2,0xC3,0xD0,0xD1,0xD2,0xD3,0xE0,0xE1,0xE2,0xE3,0xF0,0xF1,0xF2,0xF3,
  // s(3,1) 16
  0xC4,0xC5,0xC6,0xC7,0xD4,0xD5,0xD6,0xD7,0xE4,0xE5,0xE6,0xE7,0xF4,0xF5,0xF6,0xF7,
  // s(3,2) 16
  0xC8,0xC9,0xCA,0xCB,0xD8,0xD9,0xDA,0xDB,0xE8,0xE9,0xEA,0xEB,0xF8,0xF9,0xFA,0xFB,
  // D(0,0) 10
  0x00,0x10,0x11,0x20,0x21,0x22,0x30,0x31,0x32,0x33,
  // D(1,1) 10
  0x44,0x54,0x55,0x64,0x65,0x66,0x74,0x75,0x76,0x77,
  // D(2,2) 10
  0x88,0x98,0x99,0xA8,0xA9,0xAA,0xB8,0xB9,0xBA,0xBB,
  // D(3,3) 10
  0xCC,0xDC,0xDD,0xEC,0xED,0xEE,0xFC,0xFD,0xFE,0xFF
};

// ---- stage 0 (fused): blocks [0,8192) convert X fp32->bf16; [8192,11264) transpose W ----
__global__ void prep_inputs(const float* __restrict__ X, const float* __restrict__ Wq,
                            const float* __restrict__ Wk, const float* __restrict__ Wv,
                            short* __restrict__ Xb, short* __restrict__ Wt) {
  __shared__ float t[32][33];
  if (blockIdx.x < 8192) {
    long i = ((long)blockIdx.x * 256 + threadIdx.x) * 4;
    float4 v = *(const float4*)(X + i);
    short4 o;
    o.x = f2bf(v.x); o.y = f2bf(v.y); o.z = f2bf(v.z); o.w = f2bf(v.w);
    *(short4*)(Xb + i) = o;
  } else {
    int idx = blockIdx.x - 8192;           // [0,3072): z*1024 + bx*32 + by
    int z = idx >> 10, rem = idx & 1023;
    int bx = rem >> 5, by = rem & 31;
    const float* W = z == 0 ? Wq : (z == 1 ? Wk : Wv);
    short* O = Wt + (long)z * 1024 * 1024;
    int tx = threadIdx.x & 31, ty = threadIdx.x >> 5;
    int x = bx * 32 + tx;
    int y0 = by * 32;
    for (int j = ty; j < 32; j += 8)
      t[j][tx] = W[(long)(y0 + j) * 1024 + x];
    __syncthreads();
    int x2 = by * 32 + tx;
    int y2 = bx * 32;
    for (int j = ty; j < 32; j += 8)
      O[(long)(y2 + j) * 1024 + x2] = f2bf(t[tx][j]);
  }
}

// ---- stage 1: Q/K/V = X @ W ----
// z=0 -> Q [8192,1024], z=1 -> K [8192,1024], z=2 -> Vt [b][d][s]
// xOff splits the 1536-block grid into two 768-block dispatches (one residency
// round each) purely so scores/pv appear in rocprof top-5.
__global__ __launch_bounds__(256, 3) void gemm_qkv(const short* __restrict__ Xb,
                                                   const short* __restrict__ Wt,
                                                   short* __restrict__ Q, short* __restrict__ K2,
                                                   short* __restrict__ Vt, int xOff) {
  __shared__ short lA[128 * 64], lB[128 * 64];
  const int lane = threadIdx.x & 63, wave = threadIdx.x >> 6;
  const int wm = wave >> 1, wn = wave & 1;
  const int z = blockIdx.z;
  const short* Bm = Wt + (long)z * 1024 * 1024;
  const long mBase = (long)(blockIdx.x + xOff) * 128;
  const long nBase = (long)blockIdx.y * 128;

  floatx4 acc[4][4];
  const floatx4 zero = {0.f, 0.f, 0.f, 0.f};
#pragma unroll
  for (int i = 0; i < 4; ++i)
#pragma unroll
    for (int j = 0; j < 4; ++j) acc[i][j] = zero;

  for (int kt = 0; kt < 16; ++kt) {
    stage128x64(Xb, mBase, 1024, kt * 64, lA, lane, wave);
    stage128x64(Bm, nBase, 1024, kt * 64, lB, lane, wave);
    __syncthreads();
    mfma_step(lA, lB, acc, lane, wm, wn);
    __syncthreads();
  }

  if (z < 2) {
    short* out = (z == 0) ? Q : K2;
#pragma unroll
    for (int i = 0; i < 4; ++i)
#pragma unroll
      for (int j = 0; j < 4; ++j) {
        int col = (int)nBase + wn * 64 + j * 16 + (lane & 15);
#pragma unroll
        for (int r = 0; r < 4; ++r) {
          long m = mBase + wm * 64 + i * 16 + (lane >> 4) * 4 + r;
          out[m * 1024 + col] = f2bf(acc[i][j][r]);
        }
      }
  } else {
    // V transposed write: in Vt[b][d][s], the 4 r-values are s-contiguous -> short4 store
    const long bb = mBase >> 11;
    const int sBase = (int)(mBase & 2047);
#pragma unroll
    for (int i = 0; i < 4; ++i) {
      int s0 = sBase + wm * 64 + i * 16 + ((lane >> 4) << 2);
#pragma unroll
      for (int j = 0; j < 4; ++j) {
        int col = (int)nBase + wn * 64 + j * 16 + (lane & 15);
        short4 o;
        o.x = f2bf(acc[i][j][0]); o.y = f2bf(acc[i][j][1]);
        o.z = f2bf(acc[i][j][2]); o.w = f2bf(acc[i][j][3]);
        *(short4*)(Vt + ((bb * 1024 + col) * 2048 + s0)) = o;
      }
    }
  }
}

// ---- stage 2: E = exp(Q K^T / 32) on causal block pairs; row sums into l ----
// Balanced XCD schedule: class r = blockIdx.x%8 processes PAIR_LUT[r*17 + w].
__global__ __launch_bounds__(256, 3) void scores_exp(const short* __restrict__ Q,
                                                     const short* __restrict__ Kk,
                                                     short* __restrict__ E, float* __restrict__ l) {
  __shared__ short lbuf[16384];  // lA=lbuf[0:8192), lB=lbuf[8192:16384); epilogue: 128x128 E tile
  short* lA = lbuf;
  short* lB = lbuf + 8192;
  const int lane = threadIdx.x & 63, wave = threadIdx.x >> 6;
  const int wm = wave >> 1, wn = wave & 1;
  const int b = blockIdx.y;

  const int r = blockIdx.x & 7, w = blockIdx.x >> 3;  // grid.x = 136 = 8*17
  const int code = PAIR_LUT[r * 17 + w];
  const int qt = code >> 4, kt = code & 15;

  const long rowQ = (long)b * 2048 + (long)qt * 128;
  const long rowK = (long)b * 2048 + (long)kt * 128;

  floatx4 acc[4][4];
  const floatx4 zero = {0.f, 0.f, 0.f, 0.f};
#pragma unroll
  for (int i = 0; i < 4; ++i)
#pragma unroll
    for (int j = 0; j < 4; ++j) acc[i][j] = zero;

  for (int it = 0; it < 16; ++it) {
    stage128x64(Q, rowQ, 1024, it * 64, lA, lane, wave);
    stage128x64(Kk, rowK, 1024, it * 64, lB, lane, wave);
    __syncthreads();
    mfma_step(lA, lB, acc, lane, wm, wn);
    __syncthreads();
  }
  // last loop iter ended with __syncthreads(): lbuf is free for the epilogue tile.

  float* lrow = l + (long)b * 2048;
  // exp + write E tile into LDS (16B-chunk XOR swizzle to dodge bank conflicts) + row sums
#pragma unroll
  for (int i = 0; i < 4; ++i) {
#pragma unroll
    for (int rr = 0; rr < 4; ++rr) {
      int ri = wm * 64 + i * 16 + (lane >> 4) * 4 + rr;
      int qrow = qt * 128 + ri;
      float psum = 0.f;
#pragma unroll
      for (int j = 0; j < 4; ++j) {
        int ci = wn * 64 + j * 16 + (lane & 15);
        int col = kt * 128 + ci;
        float sc = acc[i][j][rr] * 0.03125f;  // 1/sqrt(1024)
        float e = (col <= qrow) ? __expf(sc) : 0.0f;
        short eb = f2bf(e);
        lbuf[ri * 128 + ((((ci >> 3) ^ (ri & 15)) << 3) | (ci & 7))] = eb;
        psum += bf2f(eb);
      }
      for (int m = 1; m < 16; m <<= 1) psum += __shfl_xor(psum, m, 64);
      if ((lane & 15) == 0) atomicAdd(&lrow[qrow], psum);
    }
  }
  __syncthreads();

  // coalesced 16B stores: 2048 chunks, 8 per thread
  short* Eb = E + (long)b * 4194304;
  const long ebase = (long)(qt * 128) * 2048 + kt * 128;
#pragma unroll
  for (int pp = 0; pp < 8; ++pp) {
    int g = pp * 256 + threadIdx.x;
    int row = g >> 4, c = g & 15;
    short8 v = *(const short8*)(lbuf + row * 128 + ((c ^ (row & 15)) << 3));
    *(short8*)(Eb + ebase + (long)row * 2048 + c * 8) = v;
  }
}

// ---- stage 3: O = (E @ V) / l, split-K + XCD-locality swizzle ----
// x = dt*24 + (wsel*8 + r): all k-slots of residue r land on XCD r; for each
// (b,dt) residue r owns {qt=15-r chunk0, chunk1, qt=r direct} = exactly 34 iters.
__global__ __launch_bounds__(256, 3) void pv_gemm(const short* __restrict__ E,
                                                  const short* __restrict__ Vt,
                                                  const float* __restrict__ l,
                                                  float* __restrict__ part,
                                                  float* __restrict__ out) {
  __shared__ short lA[128 * 64], lB[128 * 64];
  const int lane = threadIdx.x & 63, wave = threadIdx.x >> 6;
  const int wm = wave >> 1, wn = wave & 1;
  const int xx = blockIdx.x;            // [0,192)
  const int dt = xx / 24;
  const int within = xx % 24;
  const int r = within & 7, wsel = within >> 3;  // wsel in {0,1,2}
  const int b = blockIdx.y;

  int qt, it0, it1, mode;  // mode: 0 direct(/l), 1 chunk0->out raw, 2 chunk1->part raw
  if (wsel == 2) {
    qt = r; it0 = 0; it1 = (qt + 1) * 2; mode = 0;
  } else {
    qt = 15 - r;
    const int T = (qt + 1) * 2, c0 = T >> 1;
    if (wsel == 0) { it0 = 0;  it1 = c0; mode = 1; }
    else           { it0 = c0; it1 = T;  mode = 2; }
  }

  const short* Eb = E + (long)b * 2048 * 2048;
  const short* Vb = Vt + (long)b * 1024 * 2048;
  const float* lrow = l + (long)b * 2048;

  floatx4 acc[4][4];
  const floatx4 zero = {0.f, 0.f, 0.f, 0.f};
#pragma unroll
  for (int i = 0; i < 4; ++i)
#pragma unroll
    for (int j = 0; j < 4; ++j) acc[i][j] = zero;

  for (int it = it0; it < it1; ++it) {
    stage128x64(Eb, (long)qt * 128, 2048, it * 64, lA, lane, wave);
    stage128x64(Vb, (long)dt * 128, 2048, it * 64, lB, lane, wave);
    __syncthreads();
    mfma_step(lA, lB, acc, lane, wm, wn);
    __syncthreads();
  }

  if (mode == 2) {
    // partial tile index: ((b*8 + qt-8)*8 + dt) -> 128x128 fp32
    float* P = part + ((((long)b * 8 + (qt - 8)) * 8 + dt) << 14);
#pragma unroll
    for (int i = 0; i < 4; ++i)
#pragma unroll
      for (int rr = 0; rr < 4; ++rr) {
        int ri = wm * 64 + i * 16 + (lane >> 4) * 4 + rr;
#pragma unroll
        for (int j = 0; j < 4; ++j) {
          int ci = wn * 64 + j * 16 + (lane & 15);
          P[ri * 128 + ci] = acc[i][j][rr];
        }
      }
  } else {
#pragma unroll
    for (int i = 0; i < 4; ++i)
#pragma unroll
      for (int rr = 0; rr < 4; ++rr) {
        int qrow = qt * 128 + wm * 64 + i * 16 + (lane >> 4) * 4 + rr;
        float scale = (mode == 0) ? 1.0f / lrow[qrow] : 1.0f;
#pragma unroll
        for (int j = 0; j < 4; ++j) {
          int d = dt * 128 + wn * 64 + j * 16 + (lane & 15);
          out[((long)b * 2048 + qrow) * 1024 + d] = acc[i][j][rr] * scale;
        }
      }
  }
}

// ---- stage 4: rows qt>=8: out = (out + part)/l ----
__global__ void pv_reduce(float* __restrict__ out, const float* __restrict__ part,
                          const float* __restrict__ l) {
  const int idx = blockIdx.x;           // 4096 = 4b * 1024 rows
  const int b = idx >> 10;
  const int row = 1024 + (idx & 1023);  // global row in [1024, 2048)
  const int t = threadIdx.x;
  const int dt = t >> 5, dl = (t << 2) & 127;
  const float inv = 1.0f / l[((long)b << 11) + row];
  const long pbase = ((((long)b * 8 + ((row >> 7) - 8)) * 8 + dt) << 14) + ((row & 127) << 7) + dl;
  const long obase = (((long)b * 2048 + row) << 10) + (t << 2);
  float4 o = *(const float4*)(out + obase);
  float4 p = *(const float4*)(part + pbase);
  o.x = (o.x + p.x) * inv; o.y = (o.y + p.y) * inv;
  o.z = (o.z + p.z) * inv; o.w = (o.w + p.w) * inv;
  *(float4*)(out + obase) = o;
}

extern "C" void kernel_launch(void* const* d_in, const int* in_sizes, int n_in,
                              void* d_out, int out_size, void* d_ws, size_t ws_size,
                              hipStream_t stream) {
  const float* X  = (const float*)d_in[0];
  const float* Wq = (const float*)d_in[1];
  const float* Wk = (const float*)d_in[2];
  const float* Wv = (const float*)d_in[3];

  char* ws = (char*)d_ws;
  // layout (bytes): Xb 16M (reused as pv partials) | Wt 6M | Q 16M | K 16M | Vt 16M | E 32M | l 32K
  short* Xb = (short*)(ws);
  short* Wt = (short*)(ws + 16777216L);
  short* Q  = (short*)(ws + 23068672L);
  short* K2 = (short*)(ws + 39845888L);
  short* Vt = (short*)(ws + 56623104L);
  short* E  = (short*)(ws + 73400320L);
  float* l  = (float*)(ws + 106954752L);
  float* part = (float*)(ws);  // 256 tiles * 64KB = 16MB, overlays dead Xb

  hipMemsetAsync(l, 0, 4 * 2048 * sizeof(float), stream);
  prep_inputs<<<11264, 256, 0, stream>>>(X, Wq, Wk, Wv, Xb, Wt);
  gemm_qkv<<<dim3(32, 8, 3), 256, 0, stream>>>(Xb, Wt, Q, K2, Vt, 0);
  gemm_qkv<<<dim3(32, 8, 3), 256, 0, stream>>>(Xb, Wt, Q, K2, Vt, 32);
  scores_exp<<<dim3(136, 4), 256, 0, stream>>>(Q, K2, E, l);
  pv_gemm<<<dim3(192, 4), 256, 0, stream>>>(E, Vt, l, part, (float*)d_out);
  pv_reduce<<<4096, 256, 0, stream>>>((float*)d_out, part, l);
}

// Round 8
// 237.055 us; speedup vs baseline: 1.0447x; 1.0447x over previous
//
#include <hip/hip_runtime.h>

#define AS1 __attribute__((address_space(1)))
#define AS3 __attribute__((address_space(3)))

typedef __attribute__((ext_vector_type(8))) short short8;
typedef __attribute__((ext_vector_type(4))) float floatx4;

// ---- bf16 helpers (RNE; inputs are finite, no NaN/Inf handling needed) ----
__device__ __forceinline__ short f2bf(float f) {
  union { float f; unsigned u; } v; v.f = f;
  return (short)((v.u + 0x7fffu + ((v.u >> 16) & 1u)) >> 16);
}
__device__ __forceinline__ float bf2f(short s) {
  union { unsigned u; float f; } v; v.u = ((unsigned)(unsigned short)s) << 16;
  return v.f;
}

// ---- async global->LDS, 16B per lane (wave-uniform LDS base + lane*16) ----
__device__ __forceinline__ void gload_lds16(const void* g, void* l) {
  __builtin_amdgcn_global_load_lds((const AS1 unsigned*)g, (AS3 unsigned*)l, 16, 0, 0);
}

// Stage a 128x64 bf16 tile (rows rowBase..+127, cols kBase..+63) of row-major G
// (leading dim `ld` elements) into contiguous 128x64 LDS. 256 threads / 4 waves.
__device__ __forceinline__ void stage128x64(const short* __restrict__ G, long rowBase, long ld,
                                            int kBase, short* lds, int lane, int wave) {
  const short* gb = G + rowBase * ld + (long)kBase + (long)(lane >> 3) * ld + (lane & 7) * 8;
#pragma unroll
  for (int j = 0; j < 4; ++j) {
    int c = wave * 4 + j;
    gload_lds16(gb + (long)c * 8 * ld, lds + c * 512);
  }
}

// One BK=64 step of 128x128 MFMA tile compute. Wave (wm,wn) owns a 64x64 C block.
__device__ __forceinline__ void mfma_step(const short* lA, const short* lB, floatx4 acc[4][4],
                                          int lane, int wm, int wn) {
#pragma unroll
  for (int kk = 0; kk < 64; kk += 32) {
    short8 a[4], b[4];
    int kq = kk + (lane >> 4) * 8;
#pragma unroll
    for (int i = 0; i < 4; ++i) {
      a[i] = *(const short8*)(lA + (wm * 64 + i * 16 + (lane & 15)) * 64 + kq);
      b[i] = *(const short8*)(lB + (wn * 64 + i * 16 + (lane & 15)) * 64 + kq);
    }
#pragma unroll
    for (int i = 0; i < 4; ++i)
#pragma unroll
      for (int j = 0; j < 4; ++j)
        acc[i][j] = __builtin_amdgcn_mfma_f32_16x16x32_bf16(a[i], b[j], acc[i][j], 0, 0, 0);
  }
}

// Causal (qt,kt) pair LUT, supertile-major order. Entry = (qt<<4)|kt.
// Class r (=blockIdx.x%8, i.e. XCD r under round-robin dispatch) processes
// entries [r*17, r*17+17): exactly 17 pairs per XCD (perfect balance), and each
// class spans <=3 supertiles (Q/K strip locality mostly preserved).
__device__ const unsigned char PAIR_LUT[136] = {
  // s(1,0) 16
  0x40,0x41,0x42,0x43,0x50,0x51,0x52,0x53,0x60,0x61,0x62,0x63,0x70,0x71,0x72,0x73,
  // s(2,0) 16
  0x80,0x81,0x82,0x83,0x90,0x91,0x92,0x93,0xA0,0xA1,0xA2,0xA3,0xB0,0xB1,0xB2,0xB3,
  // s(2,1) 16
  0x84,0x85,0x86,0x87,0x94,0x95,0x96,0x97,0xA4,0xA5,0xA6,0xA7,0xB4,0xB5,0xB6,0xB7,
  // s(3,0) 16
  0xC0,0xC1,0xC2,0xC3,0xD0,0xD1,0xD2,0xD3,0xE0,0xE1,0xE2,0xE3,0xF0,0xF1,0xF2,0xF3,
  // s(3,1) 16
  0xC4,0xC5,0xC6,0xC7,0xD4,0xD5,0xD6,0xD7,0xE4,0xE5,0xE6,0xE7,0xF4,0xF5,0xF6,0xF7,
  // s(3,2) 16
  0xC8,0xC9,0xCA,0xCB,0xD8,0xD9,0xDA,0xDB,0xE8,0xE9,0xEA,0xEB,0xF8,0xF9,0xFA,0xFB,
  // D(0,0) 10
  0x00,0x10,0x11,0x20,0x21,0x22,0x30,0x31,0x32,0x33,
  // D(1,1) 10
  0x44,0x54,0x55,0x64,0x65,0x66,0x74,0x75,0x76,0x77,
  // D(2,2) 10
  0x88,0x98,0x99,0xA8,0xA9,0xAA,0xB8,0xB9,0xBA,0xBB,
  // D(3,3) 10
  0xCC,0xDC,0xDD,0xEC,0xED,0xEE,0xFC,0xFD,0xFE,0xFF
};

// ---- stage 0 (fused): [0,8192) convert X; [8192,11264) transpose W; [11264,11296) zero l ----
__global__ void prep_inputs(const float* __restrict__ X, const float* __restrict__ Wq,
                            const float* __restrict__ Wk, const float* __restrict__ Wv,
                            short* __restrict__ Xb, short* __restrict__ Wt,
                            float* __restrict__ l) {
  __shared__ float t[32][33];
  if (blockIdx.x < 8192) {
    long i = ((long)blockIdx.x * 256 + threadIdx.x) * 4;
    float4 v = *(const float4*)(X + i);
    short4 o;
    o.x = f2bf(v.x); o.y = f2bf(v.y); o.z = f2bf(v.z); o.w = f2bf(v.w);
    *(short4*)(Xb + i) = o;
  } else if (blockIdx.x < 11264) {
    int idx = blockIdx.x - 8192;           // [0,3072): z*1024 + bx*32 + by
    int z = idx >> 10, rem = idx & 1023;
    int bx = rem >> 5, by = rem & 31;
    const float* W = z == 0 ? Wq : (z == 1 ? Wk : Wv);
    short* O = Wt + (long)z * 1024 * 1024;
    int tx = threadIdx.x & 31, ty = threadIdx.x >> 5;
    int x = bx * 32 + tx;
    int y0 = by * 32;
    for (int j = ty; j < 32; j += 8)
      t[j][tx] = W[(long)(y0 + j) * 1024 + x];
    __syncthreads();
    int x2 = by * 32 + tx;
    int y2 = bx * 32;
    for (int j = ty; j < 32; j += 8)
      O[(long)(y2 + j) * 1024 + x2] = f2bf(t[tx][j]);
  } else {
    l[(blockIdx.x - 11264) * 256 + threadIdx.x] = 0.0f;
  }
}

// ---- stage 1: Q/K/V = X @ W ----
// z=0 -> Q [8192,1024], z=1 -> K [8192,1024], z=2 -> Vt [b][d][s]
// launch_bounds(256,4): 4 blocks/CU needs arch VGPR<=64 (acc uses 64 AGPR).
__global__ __launch_bounds__(256, 4) void gemm_qkv(const short* __restrict__ Xb,
                                                   const short* __restrict__ Wt,
                                                   short* __restrict__ Q, short* __restrict__ K2,
                                                   short* __restrict__ Vt) {
  __shared__ short lA[128 * 64], lB[128 * 64];
  const int lane = threadIdx.x & 63, wave = threadIdx.x >> 6;
  const int wm = wave >> 1, wn = wave & 1;
  const int z = blockIdx.z;
  const short* Bm = Wt + (long)z * 1024 * 1024;
  const long mBase = (long)blockIdx.x * 128;
  const long nBase = (long)blockIdx.y * 128;

  floatx4 acc[4][4];
  const floatx4 zero = {0.f, 0.f, 0.f, 0.f};
#pragma unroll
  for (int i = 0; i < 4; ++i)
#pragma unroll
    for (int j = 0; j < 4; ++j) acc[i][j] = zero;

  for (int kt = 0; kt < 16; ++kt) {
    stage128x64(Xb, mBase, 1024, kt * 64, lA, lane, wave);
    stage128x64(Bm, nBase, 1024, kt * 64, lB, lane, wave);
    __syncthreads();
    mfma_step(lA, lB, acc, lane, wm, wn);
    __syncthreads();
  }

  if (z < 2) {
    short* out = (z == 0) ? Q : K2;
#pragma unroll
    for (int i = 0; i < 4; ++i)
#pragma unroll
      for (int j = 0; j < 4; ++j) {
        int col = (int)nBase + wn * 64 + j * 16 + (lane & 15);
#pragma unroll
        for (int r = 0; r < 4; ++r) {
          long m = mBase + wm * 64 + i * 16 + (lane >> 4) * 4 + r;
          out[m * 1024 + col] = f2bf(acc[i][j][r]);
        }
      }
  } else {
    // V transposed write: in Vt[b][d][s], the 4 r-values are s-contiguous -> short4 store
    const long bb = mBase >> 11;
    const int sBase = (int)(mBase & 2047);
#pragma unroll
    for (int i = 0; i < 4; ++i) {
      int s0 = sBase + wm * 64 + i * 16 + ((lane >> 4) << 2);
#pragma unroll
      for (int j = 0; j < 4; ++j) {
        int col = (int)nBase + wn * 64 + j * 16 + (lane & 15);
        short4 o;
        o.x = f2bf(acc[i][j][0]); o.y = f2bf(acc[i][j][1]);
        o.z = f2bf(acc[i][j][2]); o.w = f2bf(acc[i][j][3]);
        *(short4*)(Vt + ((bb * 1024 + col) * 2048 + s0)) = o;
      }
    }
  }
}

// ---- stage 2: E = exp(Q K^T / 32) on causal block pairs; row sums into l ----
// Balanced XCD schedule: class r = blockIdx.x%8 processes PAIR_LUT[r*17 + w].
__global__ __launch_bounds__(256, 4) void scores_exp(const short* __restrict__ Q,
                                                     const short* __restrict__ Kk,
                                                     short* __restrict__ E, float* __restrict__ l) {
  __shared__ short lbuf[16384];  // lA=lbuf[0:8192), lB=lbuf[8192:16384); epilogue: 128x128 E tile
  short* lA = lbuf;
  short* lB = lbuf + 8192;
  const int lane = threadIdx.x & 63, wave = threadIdx.x >> 6;
  const int wm = wave >> 1, wn = wave & 1;
  const int b = blockIdx.y;

  const int r = blockIdx.x & 7, w = blockIdx.x >> 3;  // grid.x = 136 = 8*17
  const int code = PAIR_LUT[r * 17 + w];
  const int qt = code >> 4, kt = code & 15;

  const long rowQ = (long)b * 2048 + (long)qt * 128;
  const long rowK = (long)b * 2048 + (long)kt * 128;

  floatx4 acc[4][4];
  const floatx4 zero = {0.f, 0.f, 0.f, 0.f};
#pragma unroll
  for (int i = 0; i < 4; ++i)
#pragma unroll
    for (int j = 0; j < 4; ++j) acc[i][j] = zero;

  for (int it = 0; it < 16; ++it) {
    stage128x64(Q, rowQ, 1024, it * 64, lA, lane, wave);
    stage128x64(Kk, rowK, 1024, it * 64, lB, lane, wave);
    __syncthreads();
    mfma_step(lA, lB, acc, lane, wm, wn);
    __syncthreads();
  }
  // last loop iter ended with __syncthreads(): lbuf is free for the epilogue tile.

  float* lrow = l + (long)b * 2048;
  // exp + write E tile into LDS (16B-chunk XOR swizzle to dodge bank conflicts) + row sums
#pragma unroll
  for (int i = 0; i < 4; ++i) {
#pragma unroll
    for (int rr = 0; rr < 4; ++rr) {
      int ri = wm * 64 + i * 16 + (lane >> 4) * 4 + rr;
      int qrow = qt * 128 + ri;
      float psum = 0.f;
#pragma unroll
      for (int j = 0; j < 4; ++j) {
        int ci = wn * 64 + j * 16 + (lane & 15);
        int col = kt * 128 + ci;
        float sc = acc[i][j][rr] * 0.03125f;  // 1/sqrt(1024)
        float e = (col <= qrow) ? __expf(sc) : 0.0f;
        short eb = f2bf(e);
        lbuf[ri * 128 + ((((ci >> 3) ^ (ri & 15)) << 3) | (ci & 7))] = eb;
        psum += bf2f(eb);
      }
      for (int m = 1; m < 16; m <<= 1) psum += __shfl_xor(psum, m, 64);
      if ((lane & 15) == 0) atomicAdd(&lrow[qrow], psum);
    }
  }
  __syncthreads();

  // coalesced 16B stores: 2048 chunks, 8 per thread
  short* Eb = E + (long)b * 4194304;
  const long ebase = (long)(qt * 128) * 2048 + kt * 128;
#pragma unroll
  for (int pp = 0; pp < 8; ++pp) {
    int g = pp * 256 + threadIdx.x;
    int row = g >> 4, c = g & 15;
    short8 v = *(const short8*)(lbuf + row * 128 + ((c ^ (row & 15)) << 3));
    *(short8*)(Eb + ebase + (long)row * 2048 + c * 8) = v;
  }
}

// ---- stage 3: O = (E @ V) / l, split-K + XCD-locality swizzle ----
// x = dt*24 + (wsel*8 + r): all k-slots of residue r land on XCD r; for each
// (b,dt) residue r owns {qt=15-r chunk0, chunk1, qt=r direct} = exactly 34 iters.
__global__ __launch_bounds__(256, 4) void pv_gemm(const short* __restrict__ E,
                                                  const short* __restrict__ Vt,
                                                  const float* __restrict__ l,
                                                  float* __restrict__ part,
                                                  float* __restrict__ out) {
  __shared__ short lA[128 * 64], lB[128 * 64];
  const int lane = threadIdx.x & 63, wave = threadIdx.x >> 6;
  const int wm = wave >> 1, wn = wave & 1;
  const int xx = blockIdx.x;            // [0,192)
  const int dt = xx / 24;
  const int within = xx % 24;
  const int r = within & 7, wsel = within >> 3;  // wsel in {0,1,2}
  const int b = blockIdx.y;

  int qt, it0, it1, mode;  // mode: 0 direct(/l), 1 chunk0->out raw, 2 chunk1->part raw
  if (wsel == 2) {
    qt = r; it0 = 0; it1 = (qt + 1) * 2; mode = 0;
  } else {
    qt = 15 - r;
    const int T = (qt + 1) * 2, c0 = T >> 1;
    if (wsel == 0) { it0 = 0;  it1 = c0; mode = 1; }
    else           { it0 = c0; it1 = T;  mode = 2; }
  }

  const short* Eb = E + (long)b * 2048 * 2048;
  const short* Vb = Vt + (long)b * 1024 * 2048;
  const float* lrow = l + (long)b * 2048;

  floatx4 acc[4][4];
  const floatx4 zero = {0.f, 0.f, 0.f, 0.f};
#pragma unroll
  for (int i = 0; i < 4; ++i)
#pragma unroll
    for (int j = 0; j < 4; ++j) acc[i][j] = zero;

  for (int it = it0; it < it1; ++it) {
    stage128x64(Eb, (long)qt * 128, 2048, it * 64, lA, lane, wave);
    stage128x64(Vb, (long)dt * 128, 2048, it * 64, lB, lane, wave);
    __syncthreads();
    mfma_step(lA, lB, acc, lane, wm, wn);
    __syncthreads();
  }

  if (mode == 2) {
    // partial tile index: ((b*8 + qt-8)*8 + dt) -> 128x128 fp32
    float* P = part + ((((long)b * 8 + (qt - 8)) * 8 + dt) << 14);
#pragma unroll
    for (int i = 0; i < 4; ++i)
#pragma unroll
      for (int rr = 0; rr < 4; ++rr) {
        int ri = wm * 64 + i * 16 + (lane >> 4) * 4 + rr;
#pragma unroll
        for (int j = 0; j < 4; ++j) {
          int ci = wn * 64 + j * 16 + (lane & 15);
          P[ri * 128 + ci] = acc[i][j][rr];
        }
      }
  } else {
#pragma unroll
    for (int i = 0; i < 4; ++i)
#pragma unroll
      for (int rr = 0; rr < 4; ++rr) {
        int qrow = qt * 128 + wm * 64 + i * 16 + (lane >> 4) * 4 + rr;
        float scale = (mode == 0) ? 1.0f / lrow[qrow] : 1.0f;
#pragma unroll
        for (int j = 0; j < 4; ++j) {
          int d = dt * 128 + wn * 64 + j * 16 + (lane & 15);
          out[((long)b * 2048 + qrow) * 1024 + d] = acc[i][j][rr] * scale;
        }
      }
  }
}

// ---- stage 4: rows qt>=8: out = (out + part)/l ----
__global__ void pv_reduce(float* __restrict__ out, const float* __restrict__ part,
                          const float* __restrict__ l) {
  const int idx = blockIdx.x;           // 4096 = 4b * 1024 rows
  const int b = idx >> 10;
  const int row = 1024 + (idx & 1023);  // global row in [1024, 2048)
  const int t = threadIdx.x;
  const int dt = t >> 5, dl = (t << 2) & 127;
  const float inv = 1.0f / l[((long)b << 11) + row];
  const long pbase = ((((long)b * 8 + ((row >> 7) - 8)) * 8 + dt) << 14) + ((row & 127) << 7) + dl;
  const long obase = (((long)b * 2048 + row) << 10) + (t << 2);
  float4 o = *(const float4*)(out + obase);
  float4 p = *(const float4*)(part + pbase);
  o.x = (o.x + p.x) * inv; o.y = (o.y + p.y) * inv;
  o.z = (o.z + p.z) * inv; o.w = (o.w + p.w) * inv;
  *(float4*)(out + obase) = o;
}

extern "C" void kernel_launch(void* const* d_in, const int* in_sizes, int n_in,
                              void* d_out, int out_size, void* d_ws, size_t ws_size,
                              hipStream_t stream) {
  const float* X  = (const float*)d_in[0];
  const float* Wq = (const float*)d_in[1];
  const float* Wk = (const float*)d_in[2];
  const float* Wv = (const float*)d_in[3];

  char* ws = (char*)d_ws;
  // layout (bytes): Xb 16M (reused as pv partials) | Wt 6M | Q 16M | K 16M | Vt 16M | E 32M | l 32K
  short* Xb = (short*)(ws);
  short* Wt = (short*)(ws + 16777216L);
  short* Q  = (short*)(ws + 23068672L);
  short* K2 = (short*)(ws + 39845888L);
  short* Vt = (short*)(ws + 56623104L);
  short* E  = (short*)(ws + 73400320L);
  float* l  = (float*)(ws + 106954752L);
  float* part = (float*)(ws);  // 256 tiles * 64KB = 16MB, overlays dead Xb

  prep_inputs<<<11296, 256, 0, stream>>>(X, Wq, Wk, Wv, Xb, Wt, l);
  gemm_qkv<<<dim3(64, 8, 3), 256, 0, stream>>>(Xb, Wt, Q, K2, Vt);
  scores_exp<<<dim3(136, 4), 256, 0, stream>>>(Q, K2, E, l);
  pv_gemm<<<dim3(192, 4), 256, 0, stream>>>(E, Vt, l, part, (float*)d_out);
  pv_reduce<<<4096, 256, 0, stream>>>((float*)d_out, part, l);
}